// Round 5
// baseline (410.663 us; speedup 1.0000x reference)
//
#include <hip/hip_runtime.h>
#include <math.h>

#define BS   8192
#define DIM  256
#define KNEG 16
#define GAMMA (1.0f / 0.07f)
#define EXP_CLAMP 60.0f   // e^60*8192*16 ~ 1.5e31 < FLT_MAX: sums stay finite

typedef float v4f  __attribute__((ext_vector_type(4)));
typedef short s8b  __attribute__((ext_vector_type(8)));   // 8 bf16 as shorts

__device__ __forceinline__ float sat_exp(float dot) {
    float a = 2.0f * GAMMA * dot - 2.0f * GAMMA;
    return expf(fminf(a, EXP_CLAMP));
}

// branchless sorted insert, lst ascending, lst[0]=min. Caller gates on v>lst[0].
__device__ __forceinline__ void topk_insert(float (&lst)[16], float v) {
    float nl[16];
#pragma unroll
    for (int u = 0; u < 15; ++u)
        nl[u] = (v > lst[u + 1]) ? lst[u + 1] : ((v > lst[u]) ? v : lst[u]);
    nl[15] = (v > lst[15]) ? v : lst[15];
#pragma unroll
    for (int u = 0; u < 16; ++u) lst[u] = nl[u];
}

__device__ __forceinline__ unsigned short f2bf_rne(float f) {
    unsigned int u = __float_as_uint(f);
    u += 0x7FFFu + ((u >> 16) & 1u);
    return (unsigned short)(u >> 16);
}

__device__ __forceinline__ void gld_lds16(const void* g, void* l) {
    __builtin_amdgcn_global_load_lds(
        (const __attribute__((address_space(1))) void*)g,
        (__attribute__((address_space(3))) void*)l, 16, 0, 0);
}

// ---------------- init ----------------
__global__ void init_acc(float* acc) {
    if (threadIdx.x < 64) acc[threadIdx.x] = 0.0f;
}

// ------- conv_pos: fp32 -> bf16 pre-convert, fused diagonal exp sum -------
__global__ void conv_pos(const float* __restrict__ feat,
                         unsigned short* __restrict__ featbf,
                         float* __restrict__ acc) {
    int t = blockIdx.x * 256 + threadIdx.x;   // 0..262143
    int row = t >> 5;
    int c = t & 31;                           // 8-float chunk within the 256-dim
    const float* f1 = feat + (size_t)row * 512 + c * 8;
    const float* f2 = f1 + 256;
    float4 a0 = *(const float4*)(f1);
    float4 a1 = *(const float4*)(f1 + 4);
    float4 b0 = *(const float4*)(f2);
    float4 b1 = *(const float4*)(f2 + 4);
    uint4 pa, pb;
    pa.x = (unsigned)f2bf_rne(a0.x) | ((unsigned)f2bf_rne(a0.y) << 16);
    pa.y = (unsigned)f2bf_rne(a0.z) | ((unsigned)f2bf_rne(a0.w) << 16);
    pa.z = (unsigned)f2bf_rne(a1.x) | ((unsigned)f2bf_rne(a1.y) << 16);
    pa.w = (unsigned)f2bf_rne(a1.z) | ((unsigned)f2bf_rne(a1.w) << 16);
    pb.x = (unsigned)f2bf_rne(b0.x) | ((unsigned)f2bf_rne(b0.y) << 16);
    pb.y = (unsigned)f2bf_rne(b0.z) | ((unsigned)f2bf_rne(b0.w) << 16);
    pb.z = (unsigned)f2bf_rne(b1.x) | ((unsigned)f2bf_rne(b1.y) << 16);
    pb.w = (unsigned)f2bf_rne(b1.z) | ((unsigned)f2bf_rne(b1.w) << 16);
    *(uint4*)(featbf + (size_t)row * 512 + c * 8) = pa;
    *(uint4*)(featbf + (size_t)row * 512 + 256 + c * 8) = pb;
    float p = a0.x * b0.x + a0.y * b0.y + a0.z * b0.z + a0.w * b0.w
            + a1.x * b1.x + a1.y * b1.y + a1.z * b1.z + a1.w * b1.w;
#pragma unroll
    for (int o = 16; o; o >>= 1) p += __shfl_xor(p, o, 32);
    if (c == 0) atomicAdd(&acc[0], sat_exp(p));
}

// ---------------- stage1: bf16 MFMA GEMM + fused top-16 (low-pressure) -------
// Block 256 thr = 4 waves (2x2). Per ct: tile 128 rows x 128 cols, BK=64, K=256.
// 8 ct tiles per strip (strip = 1024 cols). Per-wave C = 64x64 -> acc[4][4].
// LDS: A[128 rows][128 B] @0 (16 KB), B[128 cols][128 B] @16384 (16 KB),
//      staged via global_load_lds w=16 with XOR-swizzled chunks (chunk ^= row&7)
//      so MFMA frag ds_read_b128 is ~conflict-free.
// C phase aliases staging: per-wave col-major [64 cols][68 f32] = 17408 B.
#define A_OFF   0
#define B_OFF   16384
#define CPITCH  272     // bytes per col in C region (68 floats)
#define CWAVE   17408
#define SMEM_SZ 69632
#define NSTRIPS 8

__global__ __launch_bounds__(256, 2) void stage1(const unsigned short* __restrict__ featbf,
                                                 float* __restrict__ wsTop) {
    __shared__ __align__(16) char smem[SMEM_SZ];
    const int t = threadIdx.x;
    const int l = t & 63;
    const int w = t >> 6;
    const int wy = w >> 1, wx = w & 1;
    const int quad = l >> 4, lane16 = l & 15;
    const int lr = l >> 3;                    // staging: row within 8-row group
    const int lc = (l & 7) ^ (lr & 7);        // swizzled 16-B chunk (global side)
    const int swz = lane16 & 7;               // frag-read swizzle key (row&7)
    const int rowbase = blockIdx.x * 128;
    const int strip = blockIdx.y;
    char* cw = smem + w * CWAVE;
    const int grow = rowbase + wy * 64 + l;   // row this lane owns in scan/merge

    float lst[16];
#pragma unroll
    for (int i = 0; i < 16; ++i) lst[i] = -INFINITY;

#pragma unroll 1
    for (int ct = 0; ct < 8; ++ct) {
        const int colbase = strip * 1024 + ct * 128;
        v4f acc[4][4];
#pragma unroll
        for (int mi = 0; mi < 4; ++mi)
#pragma unroll
            for (int ni = 0; ni < 4; ++ni) acc[mi][ni] = (v4f)0.0f;

#pragma unroll
        for (int s = 0; s < 4; ++s) {
            __syncthreads();   // prev frag reads / scan reads done before overwrite
            // A: 16 KB = 16 insts (4/wave, 8 rows each)
#pragma unroll
            for (int j = 0; j < 4; ++j) {
                const int rg = w * 32 + j * 8;
                gld_lds16(featbf + ((size_t)(rowbase + rg + lr) << 9) + s * 64 + lc * 8,
                          smem + A_OFF + rg * 128);
            }
            // B: 16 KB = 16 insts (4/wave, 8 cols each)
#pragma unroll
            for (int j = 0; j < 4; ++j) {
                const int rg = w * 32 + j * 8;
                gld_lds16(featbf + ((size_t)(colbase + rg + lr) << 9) + 256 + s * 64 + lc * 8,
                          smem + B_OFF + rg * 128);
            }
            __syncthreads();   // drains vmcnt -> staging visible
#pragma unroll
            for (int kh = 0; kh < 2; ++kh) {
                s8b a[4];
#pragma unroll
                for (int mi = 0; mi < 4; ++mi)
                    a[mi] = *(const s8b*)(smem + A_OFF
                        + (wy * 64 + mi * 16 + lane16) * 128
                        + ((kh * 4 + quad) ^ swz) * 16);
#pragma unroll
                for (int ni = 0; ni < 4; ++ni) {
                    s8b b = *(const s8b*)(smem + B_OFF
                        + (wx * 64 + ni * 16 + lane16) * 128
                        + ((kh * 4 + quad) ^ swz) * 16);
#pragma unroll
                    for (int mi = 0; mi < 4; ++mi)
                        acc[mi][ni] = __builtin_amdgcn_mfma_f32_16x16x32_bf16(a[mi], b, acc[mi][ni], 0, 0, 0);
                }
            }
        }
        __syncthreads();   // all waves' frag reads done; cw aliases A/B staging
        // writeback C (col-major, wave-private) + diagonal poison
#pragma unroll
        for (int ni = 0; ni < 4; ++ni) {
            int c = ni * 16 + lane16;
#pragma unroll
            for (int mi = 0; mi < 4; ++mi)
                *(v4f*)(cw + c * CPITCH + mi * 64 + quad * 16) = acc[mi][ni];
        }
        {
            int dj = grow - (colbase + wx * 64);
            if ((unsigned)dj < 64u)
                *(float*)(cw + dj * CPITCH + l * 4) = -INFINITY;
        }
        // scan own row (wave-private region; in-wave RAW handled by lgkmcnt)
        const char* crow = cw + l * 4;
#pragma unroll 4
        for (int j = 0; j < 64; ++j) {
            float v = *(const float*)(crow + j * CPITCH);
            if (v > lst[0]) topk_insert(lst, v);
        }
    }
    // ---- cross-wave merge (wx pair owns same rows) -> 16 cand per row-strip ----
    __syncthreads();
    float* mb = (float*)smem;                 // 128 rows x 16 floats = 8 KB
    if (wx == 1) {
#pragma unroll
        for (int i = 0; i < 16; i += 4)
            *(v4f*)(mb + (wy * 64 + l) * 16 + i) = *(v4f*)&lst[i];
    }
    __syncthreads();
    if (wx == 0) {
        const float* src = mb + (wy * 64 + l) * 16;
#pragma unroll
        for (int i = 0; i < 16; ++i) {
            float v = src[i];
            if (v > lst[0]) topk_insert(lst, v);
        }
        float* dst = wsTop + ((size_t)grow * NSTRIPS + strip) * 16;
#pragma unroll
        for (int i = 0; i < 16; i += 4)
            *(float4*)(dst + i) = make_float4(lst[i], lst[i + 1], lst[i + 2], lst[i + 3]);
    }
}

// ======================= legacy fallback (ws too small) ======================
__global__ void pos_kernel(const float* __restrict__ feat, float* __restrict__ acc) {
    int t = blockIdx.x * 256 + threadIdx.x;
    int row = t >> 4;
    int lane16 = t & 15;
    const float* f = feat + (size_t)row * 512 + lane16 * 16;
    float p = 0.0f;
#pragma unroll
    for (int q = 0; q < 16; q += 4) {
        float4 a = *(const float4*)(f + q);
        float4 b = *(const float4*)(f + 256 + q);
        p += a.x * b.x + a.y * b.y + a.z * b.z + a.w * b.w;
    }
#pragma unroll
    for (int o = 8; o; o >>= 1) p += __shfl_xor(p, o, 16);
    if (lane16 == 0) atomicAdd(&acc[0], sat_exp(p));
}

#define L_AOFF   0
#define L_BOFF   10240
#define L_PITCH  80
__global__ __launch_bounds__(256, 2) void stage1_legacy(const float* __restrict__ feat,
                                                        float* __restrict__ wsTop) {
    __shared__ __align__(16) char smem[SMEM_SZ];
    const int t = threadIdx.x;
    const int l = t & 63;
    const int w = t >> 6;
    const int wy = w >> 1, wx = w & 1;
    const int quad = l >> 4, lane16 = l & 15;
    const int rowbase = blockIdx.x * 128;
    const int strip = blockIdx.y;
    char* cw = smem + w * CWAVE;
    const int grow = rowbase + wy * 64 + l;

    float lst[16];
#pragma unroll
    for (int i = 0; i < 16; ++i) lst[i] = -INFINITY;

    for (int ct = 0; ct < 4; ++ct) {
        const int colbase = strip * 1024 + ct * 256;
        v4f acc[4][8];
#pragma unroll
        for (int mi = 0; mi < 4; ++mi)
#pragma unroll
            for (int ni = 0; ni < 8; ++ni) acc[mi][ni] = (v4f)0.0f;
        for (int s = 0; s < 8; ++s) {
            const int k0 = s * 32;
            __syncthreads();
#pragma unroll
            for (int i = 0; i < 4; ++i) {
                int c = i * 256 + t;
                int r = c >> 3, chk = c & 7;
                float4 v = *(const float4*)(feat + (size_t)(rowbase + r) * 512 + k0 + chk * 4);
                uint2 pk;
                pk.x = (unsigned)f2bf_rne(v.x) | ((unsigned)f2bf_rne(v.y) << 16);
                pk.y = (unsigned)f2bf_rne(v.z) | ((unsigned)f2bf_rne(v.w) << 16);
                *(uint2*)(smem + L_AOFF + r * L_PITCH + chk * 8) = pk;
            }
#pragma unroll
            for (int i = 0; i < 8; ++i) {
                int c = i * 256 + t;
                int n = c >> 3, chk = c & 7;
                float4 v = *(const float4*)(feat + (size_t)(colbase + n) * 512 + 256 + k0 + chk * 4);
                uint2 pk;
                pk.x = (unsigned)f2bf_rne(v.x) | ((unsigned)f2bf_rne(v.y) << 16);
                pk.y = (unsigned)f2bf_rne(v.z) | ((unsigned)f2bf_rne(v.w) << 16);
                *(uint2*)(smem + L_BOFF + n * L_PITCH + chk * 8) = pk;
            }
            __syncthreads();
            s8b a[4];
#pragma unroll
            for (int mi = 0; mi < 4; ++mi)
                a[mi] = *(const s8b*)(smem + L_AOFF + (wy * 64 + mi * 16 + lane16) * L_PITCH + quad * 16);
#pragma unroll
            for (int ni = 0; ni < 8; ++ni) {
                s8b b = *(const s8b*)(smem + L_BOFF + (wx * 128 + ni * 16 + lane16) * L_PITCH + quad * 16);
#pragma unroll
                for (int mi = 0; mi < 4; ++mi)
                    acc[mi][ni] = __builtin_amdgcn_mfma_f32_16x16x32_bf16(a[mi], b, acc[mi][ni], 0, 0, 0);
            }
        }
#pragma unroll
        for (int h = 0; h < 2; ++h) {
            __syncthreads();
#pragma unroll
            for (int ni = 0; ni < 4; ++ni) {
                int c = ni * 16 + lane16;
#pragma unroll
                for (int mi = 0; mi < 4; ++mi)
                    *(v4f*)(cw + c * CPITCH + mi * 64 + quad * 16) = acc[mi][h * 4 + ni];
            }
            __syncthreads();
            const int gc0 = colbase + wx * 128 + h * 64;
            const int dj = grow - gc0;
#pragma unroll
            for (int j = 0; j < 64; ++j) {
                float v = *(const float*)(cw + j * CPITCH + l * 4);
                if (v > lst[0] && j != dj) topk_insert(lst, v);
            }
        }
    }
    float* dst = wsTop + (size_t)grow * 256 + strip * 32 + wx * 16;
#pragma unroll
    for (int i = 0; i < 16; i += 4)
        *(float4*)(dst + i) = make_float4(lst[i], lst[i + 1], lst[i + 2], lst[i + 3]);
}

// ---------------- stage2: per-row merge of ncand -> top-16 -> sum(exp) -------
__global__ void stage2(const float* __restrict__ wsTop, float* __restrict__ acc, int ncand) {
    int row = blockIdx.x * blockDim.x + threadIdx.x;
    if (row >= BS) return;
    const float* src = wsTop + (size_t)row * ncand;
    float lst[16];
#pragma unroll
    for (int i = 0; i < 16; ++i) lst[i] = -INFINITY;
    for (int c = 0; c < ncand; c += 4) {
        float4 v4 = *(const float4*)(src + c);
        float vv[4] = {v4.x, v4.y, v4.z, v4.w};
#pragma unroll
        for (int j = 0; j < 4; ++j)
            if (vv[j] > lst[0]) topk_insert(lst, vv[j]);
    }
    float s = 0.0f;
#pragma unroll
    for (int i = 0; i < 16; ++i) s += sat_exp(lst[i]);
    atomicAdd(&acc[1], s);
}

// ---------------- final (sanitize inf/nan for harness compare) ----------------
__device__ __forceinline__ float finite_or(float x, float repl) {
    if (isnan(x)) return repl;
    if (isinf(x)) return x > 0.0f ? 3.0e38f : -3.0e38f;
    return x;
}

__global__ void final_kernel(const float* __restrict__ acc, float* __restrict__ out) {
    if (threadIdx.x == 0) {
        out[0] = finite_or(-(acc[0] / (float)BS), 0.0f);
        out[1] = finite_or(acc[1] / (float)(BS * KNEG), 0.0f);
    }
}

extern "C" void kernel_launch(void* const* d_in, const int* in_sizes, int n_in,
                              void* d_out, int out_size, void* d_ws, size_t ws_size,
                              hipStream_t stream) {
    const float* feat = (const float*)d_in[0];
    float* out = (float*)d_out;
    float* acc = (float*)d_ws;

    // new path layout: acc(256 B) | featbf (8 MB) | wsTop (4 MB)
    unsigned short* featbf = (unsigned short*)(acc + 64);
    float* wsTop = (float*)(featbf + (size_t)BS * 512);
    const size_t need_new = 256 + (size_t)BS * 512 * 2 + (size_t)BS * NSTRIPS * 16 * 4;

    init_acc<<<1, 64, 0, stream>>>(acc);
    if (ws_size >= need_new) {
        conv_pos<<<1024, 256, 0, stream>>>(feat, featbf, acc);
        stage1<<<dim3(64, NSTRIPS), 256, 0, stream>>>(featbf, wsTop);
        stage2<<<32, 256, 0, stream>>>(wsTop, acc, NSTRIPS * 16);
    } else {
        float* wsTopL = acc + 64;   // 8 MB legacy layout
        pos_kernel<<<512, 256, 0, stream>>>(feat, acc);
        stage1_legacy<<<dim3(64, 8), 256, 0, stream>>>(feat, wsTopL);
        stage2<<<32, 256, 0, stream>>>(wsTopL, acc, 256);
    }
    final_kernel<<<1, 1, 0, stream>>>(acc, out);
}

// Round 6
// 248.027 us; speedup vs baseline: 1.6557x; 1.6557x over previous
//
#include <hip/hip_runtime.h>
#include <math.h>

#define BS   8192
#define DIM  256
#define KNEG 16
#define GAMMA (1.0f / 0.07f)
#define EXP_CLAMP 60.0f   // e^60*8192*16 ~ 1.5e31 < FLT_MAX: sums stay finite
#define NSTRIPS 8

typedef float v4f  __attribute__((ext_vector_type(4)));
typedef short s8b  __attribute__((ext_vector_type(8)));   // 8 bf16 as shorts

__device__ __forceinline__ float sat_exp(float dot) {
    float a = 2.0f * GAMMA * dot - 2.0f * GAMMA;
    return expf(fminf(a, EXP_CLAMP));
}

// branchless sorted insert, lst ascending, lst[0]=min. Caller gates on v>lst[0].
__device__ __forceinline__ void topk_insert(float (&lst)[16], float v) {
    float nl[16];
#pragma unroll
    for (int u = 0; u < 15; ++u)
        nl[u] = (v > lst[u + 1]) ? lst[u + 1] : ((v > lst[u]) ? v : lst[u]);
    nl[15] = (v > lst[15]) ? v : lst[15];
#pragma unroll
    for (int u = 0; u < 16; ++u) lst[u] = nl[u];
}

__device__ __forceinline__ unsigned short f2bf_rne(float f) {
    unsigned int u = __float_as_uint(f);
    u += 0x7FFFu + ((u >> 16) & 1u);
    return (unsigned short)(u >> 16);
}

__device__ __forceinline__ void gld_lds16(const void* g, void* l) {
    __builtin_amdgcn_global_load_lds(
        (const __attribute__((address_space(1))) void*)g,
        (__attribute__((address_space(3))) void*)l, 16, 0, 0);
}

__device__ __forceinline__ float finite_or(float x, float repl) {
    if (isnan(x)) return repl;
    if (isinf(x)) return x > 0.0f ? 3.0e38f : -3.0e38f;
    return x;
}

// ------- conv_pos: fp32 -> bf16 pre-convert + per-block diagonal partials -----
// 32 threads per row; grid 1024 x 256.
__global__ void conv_pos(const float* __restrict__ feat,
                         unsigned short* __restrict__ featbf,
                         float* __restrict__ partialPos) {
    __shared__ float red[8];
    int t = blockIdx.x * 256 + threadIdx.x;   // 0..262143
    int row = t >> 5;
    int c = t & 31;                           // 8-float chunk within the 256-dim
    const float* f1 = feat + (size_t)row * 512 + c * 8;
    const float* f2 = f1 + 256;
    float4 a0 = *(const float4*)(f1);
    float4 a1 = *(const float4*)(f1 + 4);
    float4 b0 = *(const float4*)(f2);
    float4 b1 = *(const float4*)(f2 + 4);
    uint4 pa, pb;
    pa.x = (unsigned)f2bf_rne(a0.x) | ((unsigned)f2bf_rne(a0.y) << 16);
    pa.y = (unsigned)f2bf_rne(a0.z) | ((unsigned)f2bf_rne(a0.w) << 16);
    pa.z = (unsigned)f2bf_rne(a1.x) | ((unsigned)f2bf_rne(a1.y) << 16);
    pa.w = (unsigned)f2bf_rne(a1.z) | ((unsigned)f2bf_rne(a1.w) << 16);
    pb.x = (unsigned)f2bf_rne(b0.x) | ((unsigned)f2bf_rne(b0.y) << 16);
    pb.y = (unsigned)f2bf_rne(b0.z) | ((unsigned)f2bf_rne(b0.w) << 16);
    pb.z = (unsigned)f2bf_rne(b1.x) | ((unsigned)f2bf_rne(b1.y) << 16);
    pb.w = (unsigned)f2bf_rne(b1.z) | ((unsigned)f2bf_rne(b1.w) << 16);
    *(uint4*)(featbf + (size_t)row * 512 + c * 8) = pa;
    *(uint4*)(featbf + (size_t)row * 512 + 256 + c * 8) = pb;
    float p = a0.x * b0.x + a0.y * b0.y + a0.z * b0.z + a0.w * b0.w
            + a1.x * b1.x + a1.y * b1.y + a1.z * b1.z + a1.w * b1.w;
#pragma unroll
    for (int o = 16; o; o >>= 1) p += __shfl_xor(p, o, 32);
    if (c == 0) red[threadIdx.x >> 5] = sat_exp(p);
    __syncthreads();
    if (threadIdx.x == 0) {
        float s = 0.0f;
#pragma unroll
        for (int i = 0; i < 8; ++i) s += red[i];
        partialPos[blockIdx.x] = s;
    }
}

// ---------------- stage1: operand-swapped bf16 MFMA GEMM, register top-16 ----
// Block 256 thr = 4 waves (wy=rows-half, wx=cols-half).
// Block tile: N=64 F1-rows x M=128 F2-cols per ct; 8 ct per strip (1024 cols).
// MFMA: A-operand = F2 (M), B-operand = F1 (N) => D col(lane16) = F1 row.
// Each lane owns 2 rows (ni=0,1); top-16 lists live in registers; no C-LDS.
// LDS 40 KB: B resident [64 rows][512 B] @0 (32 KB, whole K=256, XOR-swizzled),
//            A per k-step [128 rows][64 B] @32768 (8 KB, BK=32, XOR-swizzled).
#define A_OFF 32768
#define S1_LDS 40960

__global__ __launch_bounds__(256, 4) void stage1(const unsigned short* __restrict__ featbf,
                                                 float* __restrict__ wsTop) {
    __shared__ __align__(16) char smem[S1_LDS];
    const int t = threadIdx.x;
    const int l = t & 63;
    const int w = t >> 6;
    const int wy = w >> 1, wx = w & 1;
    const int quad = l >> 4, lane16 = l & 15;
    const int nbase = blockIdx.x * 64;
    const int strip = blockIdx.y;

    // ---- stage B resident: rows nbase..nbase+63 (F1), all K. 8 insts/wave. ----
    // inst j covers rows 2j,2j+1; lane l: row r=2j+(l>>5), slot sl=l&31,
    // content = global chunk c = sl ^ (r&31)  (16-B chunks, 32 per row).
#pragma unroll
    for (int jj = 0; jj < 8; ++jj) {
        int j = w * 8 + jj;
        int r = 2 * j + (l >> 5);
        int c = (l & 31) ^ (r & 31);
        gld_lds16(featbf + ((size_t)(nbase + r) << 9) + c * 8, smem + j * 1024);
    }
    // (drained by the first k-step's post-stage barrier)

    float lst[2][16];
#pragma unroll
    for (int ni = 0; ni < 2; ++ni)
#pragma unroll
        for (int i = 0; i < 16; ++i) lst[ni][i] = -INFINITY;

    const int akey = (quad ^ ((lane16 >> 1) & 3)) * 16;   // A frag slot offset

#pragma unroll 1
    for (int ct = 0; ct < 8; ++ct) {
        const int ctbase = strip * 1024 + ct * 128;
        v4f acc[4][2];
#pragma unroll
        for (int mi = 0; mi < 4; ++mi)
#pragma unroll
            for (int ni = 0; ni < 2; ++ni) acc[mi][ni] = (v4f)0.0f;

#pragma unroll
        for (int s = 0; s < 8; ++s) {
            __syncthreads();   // prev step's A frag reads done before restage
            // stage A: 128 F2-rows x 32 K (8 KB), 2 insts/wave; inst j covers
            // 16 rows; lane l: row r=16j+(l>>2), slot sl=l&3,
            // content chunk c = sl ^ ((r>>1)&3).
#pragma unroll
            for (int jj = 0; jj < 2; ++jj) {
                int j = w * 2 + jj;
                int r = 16 * j + (l >> 2);
                int c = (l & 3) ^ ((r >> 1) & 3);
                gld_lds16(featbf + ((size_t)(ctbase + r) << 9) + 256 + s * 32 + c * 8,
                          smem + A_OFF + j * 1024);
            }
            __syncthreads();   // vmcnt(0) drain: staging visible
            s8b a[4];
#pragma unroll
            for (int mi = 0; mi < 4; ++mi)
                a[mi] = *(const s8b*)(smem + A_OFF
                    + (wx * 64 + mi * 16 + lane16) * 64 + akey);
#pragma unroll
            for (int ni = 0; ni < 2; ++ni) {
                int nl31 = ni * 16 + lane16;   // n_local & 31
                s8b b = *(const s8b*)(smem
                    + (wy * 32 + nl31) * 512 + (((s * 4 + quad) ^ nl31) & 31) * 16);
#pragma unroll
                for (int mi = 0; mi < 4; ++mi)
                    acc[mi][ni] = __builtin_amdgcn_mfma_f32_16x16x32_bf16(a[mi], b, acc[mi][ni], 0, 0, 0);
            }
        }
        // ---- register scan: lane's values all belong to row (per ni) ----
#pragma unroll
        for (int ni = 0; ni < 2; ++ni) {
            const int row = nbase + wy * 32 + ni * 16 + lane16;
#pragma unroll
            for (int mi = 0; mi < 4; ++mi) {
                const int c0 = ctbase + wx * 64 + mi * 16 + quad * 4;
#pragma unroll
                for (int r4 = 0; r4 < 4; ++r4) {
                    float v = acc[mi][ni][r4];
                    if (c0 + r4 == row) v = -INFINITY;    // diagonal mask
                    if (v > lst[ni][0]) topk_insert(lst[ni], v);
                }
            }
        }
    }
    // ---- quad merge via shfl: lanes lane16+q*16 hold the same rows ----
#pragma unroll
    for (int ni = 0; ni < 2; ++ni)
#pragma unroll
        for (int q = 1; q < 4; ++q)
#pragma unroll
            for (int i = 0; i < 16; ++i) {
                float v = __shfl(lst[ni][i], lane16 + q * 16, 64);
                if (quad == 0 && v > lst[ni][0]) topk_insert(lst[ni], v);
            }
    // ---- wx merge via LDS (A region, all frag reads done) ----
    __syncthreads();
    float* mrg = (float*)(smem + A_OFF);   // 64 rows x 16 f32 = 4 KB
    if (wx == 1 && quad == 0) {
#pragma unroll
        for (int ni = 0; ni < 2; ++ni) {
            int rl = wy * 32 + ni * 16 + lane16;
#pragma unroll
            for (int i = 0; i < 16; i += 4)
                *(v4f*)(mrg + rl * 16 + i) = *(v4f*)&lst[ni][i];
        }
    }
    __syncthreads();
    if (wx == 0 && quad == 0) {
#pragma unroll
        for (int ni = 0; ni < 2; ++ni) {
            const int rl = wy * 32 + ni * 16 + lane16;
#pragma unroll
            for (int i = 0; i < 16; ++i) {
                float v = mrg[rl * 16 + i];
                if (v > lst[ni][0]) topk_insert(lst[ni], v);
            }
            float* dst = wsTop + ((size_t)(nbase + rl) * NSTRIPS + strip) * 16;
#pragma unroll
            for (int i = 0; i < 16; i += 4)
                *(float4*)(dst + i) = make_float4(lst[ni][i], lst[ni][i + 1],
                                                  lst[ni][i + 2], lst[ni][i + 3]);
        }
    }
}

// ------- stage2: per-row merge of 128 candidates -> top-16 -> partial sums ----
__global__ void stage2(const float* __restrict__ wsTop, float* __restrict__ partialNeg) {
    __shared__ float red[256];
    int row = blockIdx.x * 256 + threadIdx.x;
    const float* src = wsTop + (size_t)row * (NSTRIPS * 16);
    float lst[16];
#pragma unroll
    for (int i = 0; i < 16; ++i) lst[i] = -INFINITY;
    for (int c = 0; c < NSTRIPS * 16; c += 4) {
        float4 v4 = *(const float4*)(src + c);
        float vv[4] = {v4.x, v4.y, v4.z, v4.w};
#pragma unroll
        for (int j = 0; j < 4; ++j)
            if (vv[j] > lst[0]) topk_insert(lst, vv[j]);
    }
    float s = 0.0f;
#pragma unroll
    for (int i = 0; i < 16; ++i) s += sat_exp(lst[i]);
    red[threadIdx.x] = s;
    __syncthreads();
    for (int o = 128; o; o >>= 1) {
        if (threadIdx.x < o) red[threadIdx.x] += red[threadIdx.x + o];
        __syncthreads();
    }
    if (threadIdx.x == 0) partialNeg[blockIdx.x] = red[0];
}

// ---------------- final: reduce partials, sanitize inf/nan ----------------
__global__ void final_kernel(const float* __restrict__ partialPos,
                             const float* __restrict__ partialNeg,
                             float* __restrict__ out) {
    __shared__ float w1[4], w2[4];
    float sp = 0.0f, sn = 0.0f;
    for (int i = threadIdx.x; i < 1024; i += 256) sp += partialPos[i];
    if (threadIdx.x < 32) sn = partialNeg[threadIdx.x];
#pragma unroll
    for (int o = 32; o; o >>= 1) {
        sp += __shfl_xor(sp, o, 64);
        sn += __shfl_xor(sn, o, 64);
    }
    if ((threadIdx.x & 63) == 0) {
        w1[threadIdx.x >> 6] = sp;
        w2[threadIdx.x >> 6] = sn;
    }
    __syncthreads();
    if (threadIdx.x == 0) {
        float tp = w1[0] + w1[1] + w1[2] + w1[3];
        float tn = w2[0] + w2[1] + w2[2] + w2[3];
        out[0] = finite_or(-(tp / (float)BS), 0.0f);
        out[1] = finite_or(tn / (float)(BS * KNEG), 0.0f);
    }
}

// ======================= legacy fallback (ws too small) ======================
__global__ void init_acc(float* acc) {
    if (threadIdx.x < 64) acc[threadIdx.x] = 0.0f;
}

__global__ void pos_kernel(const float* __restrict__ feat, float* __restrict__ acc) {
    int t = blockIdx.x * 256 + threadIdx.x;
    int row = t >> 4;
    int lane16 = t & 15;
    const float* f = feat + (size_t)row * 512 + lane16 * 16;
    float p = 0.0f;
#pragma unroll
    for (int q = 0; q < 16; q += 4) {
        float4 a = *(const float4*)(f + q);
        float4 b = *(const float4*)(f + 256 + q);
        p += a.x * b.x + a.y * b.y + a.z * b.z + a.w * b.w;
    }
#pragma unroll
    for (int o = 8; o; o >>= 1) p += __shfl_xor(p, o, 16);
    if (lane16 == 0) atomicAdd(&acc[0], sat_exp(p));
}

#define L_AOFF   0
#define L_BOFF   10240
#define L_PITCH  80
#define CPITCH  272
#define CWAVE   17408
#define L_SMEM  69632
__global__ __launch_bounds__(256, 2) void stage1_legacy(const float* __restrict__ feat,
                                                        float* __restrict__ wsTop) {
    __shared__ __align__(16) char smem[L_SMEM];
    const int t = threadIdx.x;
    const int l = t & 63;
    const int w = t >> 6;
    const int wy = w >> 1, wx = w & 1;
    const int quad = l >> 4, lane16 = l & 15;
    const int rowbase = blockIdx.x * 128;
    const int strip = blockIdx.y;
    char* cw = smem + w * CWAVE;
    const int grow = rowbase + wy * 64 + l;

    float lst[16];
#pragma unroll
    for (int i = 0; i < 16; ++i) lst[i] = -INFINITY;

    for (int ct = 0; ct < 4; ++ct) {
        const int colbase = strip * 1024 + ct * 256;
        v4f acc[4][8];
#pragma unroll
        for (int mi = 0; mi < 4; ++mi)
#pragma unroll
            for (int ni = 0; ni < 8; ++ni) acc[mi][ni] = (v4f)0.0f;
        for (int s = 0; s < 8; ++s) {
            const int k0 = s * 32;
            __syncthreads();
#pragma unroll
            for (int i = 0; i < 4; ++i) {
                int c = i * 256 + t;
                int r = c >> 3, chk = c & 7;
                float4 v = *(const float4*)(feat + (size_t)(rowbase + r) * 512 + k0 + chk * 4);
                uint2 pk;
                pk.x = (unsigned)f2bf_rne(v.x) | ((unsigned)f2bf_rne(v.y) << 16);
                pk.y = (unsigned)f2bf_rne(v.z) | ((unsigned)f2bf_rne(v.w) << 16);
                *(uint2*)(smem + L_AOFF + r * L_PITCH + chk * 8) = pk;
            }
#pragma unroll
            for (int i = 0; i < 8; ++i) {
                int c = i * 256 + t;
                int n = c >> 3, chk = c & 7;
                float4 v = *(const float4*)(feat + (size_t)(colbase + n) * 512 + 256 + k0 + chk * 4);
                uint2 pk;
                pk.x = (unsigned)f2bf_rne(v.x) | ((unsigned)f2bf_rne(v.y) << 16);
                pk.y = (unsigned)f2bf_rne(v.z) | ((unsigned)f2bf_rne(v.w) << 16);
                *(uint2*)(smem + L_BOFF + n * L_PITCH + chk * 8) = pk;
            }
            __syncthreads();
            s8b a[4];
#pragma unroll
            for (int mi = 0; mi < 4; ++mi)
                a[mi] = *(const s8b*)(smem + L_AOFF + (wy * 64 + mi * 16 + lane16) * L_PITCH + quad * 16);
#pragma unroll
            for (int ni = 0; ni < 8; ++ni) {
                s8b b = *(const s8b*)(smem + L_BOFF + (wx * 128 + ni * 16 + lane16) * L_PITCH + quad * 16);
#pragma unroll
                for (int mi = 0; mi < 4; ++mi)
                    acc[mi][ni] = __builtin_amdgcn_mfma_f32_16x16x32_bf16(a[mi], b, acc[mi][ni], 0, 0, 0);
            }
        }
#pragma unroll
        for (int h = 0; h < 2; ++h) {
            __syncthreads();
#pragma unroll
            for (int ni = 0; ni < 4; ++ni) {
                int c = ni * 16 + lane16;
#pragma unroll
                for (int mi = 0; mi < 4; ++mi)
                    *(v4f*)(cw + c * CPITCH + mi * 64 + quad * 16) = acc[mi][h * 4 + ni];
            }
            __syncthreads();
            const int gc0 = colbase + wx * 128 + h * 64;
            const int dj = grow - gc0;
#pragma unroll
            for (int j = 0; j < 64; ++j) {
                float v = *(const float*)(cw + j * CPITCH + l * 4);
                if (v > lst[0] && j != dj) topk_insert(lst, v);
            }
        }
    }
    float* dst = wsTop + (size_t)grow * 256 + strip * 32 + wx * 16;
#pragma unroll
    for (int i = 0; i < 16; i += 4)
        *(float4*)(dst + i) = make_float4(lst[i], lst[i + 1], lst[i + 2], lst[i + 3]);
}

__global__ void stage2_legacy(const float* __restrict__ wsTop, float* __restrict__ acc) {
    int row = blockIdx.x * blockDim.x + threadIdx.x;
    if (row >= BS) return;
    const float* src = wsTop + (size_t)row * 256;
    float lst[16];
#pragma unroll
    for (int i = 0; i < 16; ++i) lst[i] = -INFINITY;
    for (int c = 0; c < 256; c += 4) {
        float4 v4 = *(const float4*)(src + c);
        float vv[4] = {v4.x, v4.y, v4.z, v4.w};
#pragma unroll
        for (int j = 0; j < 4; ++j)
            if (vv[j] > lst[0]) topk_insert(lst, vv[j]);
    }
    float s = 0.0f;
#pragma unroll
    for (int i = 0; i < 16; ++i) s += sat_exp(lst[i]);
    atomicAdd(&acc[1], s);
}

__global__ void final_legacy(const float* __restrict__ acc, float* __restrict__ out) {
    if (threadIdx.x == 0) {
        out[0] = finite_or(-(acc[0] / (float)BS), 0.0f);
        out[1] = finite_or(acc[1] / (float)(BS * KNEG), 0.0f);
    }
}

extern "C" void kernel_launch(void* const* d_in, const int* in_sizes, int n_in,
                              void* d_out, int out_size, void* d_ws, size_t ws_size,
                              hipStream_t stream) {
    const float* feat = (const float*)d_in[0];
    float* out = (float*)d_out;

    // new path layout: featbf 8 MB | wsTop 4 MB | partialPos 4 KB | partialNeg 128 B
    unsigned short* featbf = (unsigned short*)d_ws;
    float* wsTop = (float*)(featbf + (size_t)BS * 512);
    float* partialPos = wsTop + (size_t)BS * NSTRIPS * 16;
    float* partialNeg = partialPos + 1024;
    const size_t need_new = (size_t)BS * 512 * 2 + (size_t)BS * NSTRIPS * 16 * 4
                          + (1024 + 32) * 4;

    if (ws_size >= need_new) {
        conv_pos<<<1024, 256, 0, stream>>>(feat, featbf, partialPos);
        stage1<<<dim3(128, NSTRIPS), 256, 0, stream>>>(featbf, wsTop);
        stage2<<<32, 256, 0, stream>>>(wsTop, partialNeg);
        final_kernel<<<1, 256, 0, stream>>>(partialPos, partialNeg, out);
    } else {
        float* acc = (float*)d_ws;
        float* wsTopL = acc + 64;   // 8 MB legacy layout
        init_acc<<<1, 64, 0, stream>>>(acc);
        pos_kernel<<<512, 256, 0, stream>>>(feat, acc);
        stage1_legacy<<<dim3(64, 8), 256, 0, stream>>>(feat, wsTopL);
        stage2_legacy<<<32, 256, 0, stream>>>(wsTopL, acc);
        final_legacy<<<1, 1, 0, stream>>>(acc, out);
    }
}

// Round 7
// 139.266 us; speedup vs baseline: 2.9488x; 1.7810x over previous
//
#include <hip/hip_runtime.h>
#include <math.h>

#define BS   8192
#define DIM  256
#define KNEG 16
#define GAMMA (1.0f / 0.07f)
#define EXP_CLAMP 60.0f   // e^60*8192*16 ~ 1.5e31 < FLT_MAX: sums stay finite
#define NSTRIPS 8

typedef float v4f  __attribute__((ext_vector_type(4)));
typedef short s8b  __attribute__((ext_vector_type(8)));   // 8 bf16 as shorts

__device__ __forceinline__ float sat_exp(float dot) {
    float a = 2.0f * GAMMA * dot - 2.0f * GAMMA;
    return expf(fminf(a, EXP_CLAMP));
}

// ---- branchless bitonic sort of 16 regs, ascending (80 CE, fully unrolled) ----
__device__ __forceinline__ void sort16(float (&a)[16]) {
#pragma unroll
    for (int k = 2; k <= 16; k <<= 1) {
#pragma unroll
        for (int j = k >> 1; j > 0; j >>= 1) {
#pragma unroll
            for (int i = 0; i < 16; ++i) {
                int ixj = i ^ j;
                if (ixj > i) {
                    float lo = fminf(a[i], a[ixj]);
                    float hi = fmaxf(a[i], a[ixj]);
                    bool up = ((i & k) == 0);
                    a[i]   = up ? lo : hi;
                    a[ixj] = up ? hi : lo;
                }
            }
        }
    }
}

// ---- merge two ascending sorted-16 lists, keep top-16 ascending (48 CE) ----
// reverse-max gives the top-16 multiset as a bitonic sequence; clean log16 stages.
__device__ __forceinline__ void merge_top16(float (&lst)[16], const float (&nw)[16]) {
    float t[16];
#pragma unroll
    for (int i = 0; i < 16; ++i) t[i] = fmaxf(lst[i], nw[15 - i]);
#pragma unroll
    for (int j = 8; j > 0; j >>= 1) {
#pragma unroll
        for (int i = 0; i < 16; ++i) {
            int ixj = i ^ j;
            if (ixj > i) {
                float lo = fminf(t[i], t[ixj]);
                float hi = fmaxf(t[i], t[ixj]);
                t[i] = lo; t[ixj] = hi;
            }
        }
    }
#pragma unroll
    for (int i = 0; i < 16; ++i) lst[i] = t[i];
}

// legacy insertion helper (fallback path only)
__device__ __forceinline__ void topk_insert(float (&lst)[16], float v) {
    float nl[16];
#pragma unroll
    for (int u = 0; u < 15; ++u)
        nl[u] = (v > lst[u + 1]) ? lst[u + 1] : ((v > lst[u]) ? v : lst[u]);
    nl[15] = (v > lst[15]) ? v : lst[15];
#pragma unroll
    for (int u = 0; u < 16; ++u) lst[u] = nl[u];
}

__device__ __forceinline__ unsigned short f2bf_rne(float f) {
    unsigned int u = __float_as_uint(f);
    u += 0x7FFFu + ((u >> 16) & 1u);
    return (unsigned short)(u >> 16);
}

__device__ __forceinline__ void gld_lds16(const void* g, void* l) {
    __builtin_amdgcn_global_load_lds(
        (const __attribute__((address_space(1))) void*)g,
        (__attribute__((address_space(3))) void*)l, 16, 0, 0);
}

__device__ __forceinline__ float finite_or(float x, float repl) {
    if (isnan(x)) return repl;
    if (isinf(x)) return x > 0.0f ? 3.0e38f : -3.0e38f;
    return x;
}

// ------- conv_pos: fp32 -> bf16 pre-convert + per-block diagonal partials -----
__global__ void conv_pos(const float* __restrict__ feat,
                         unsigned short* __restrict__ featbf,
                         float* __restrict__ partialPos) {
    __shared__ float red[8];
    int t = blockIdx.x * 256 + threadIdx.x;   // 0..262143
    int row = t >> 5;
    int c = t & 31;                           // 8-float chunk within the 256-dim
    const float* f1 = feat + (size_t)row * 512 + c * 8;
    const float* f2 = f1 + 256;
    float4 a0 = *(const float4*)(f1);
    float4 a1 = *(const float4*)(f1 + 4);
    float4 b0 = *(const float4*)(f2);
    float4 b1 = *(const float4*)(f2 + 4);
    uint4 pa, pb;
    pa.x = (unsigned)f2bf_rne(a0.x) | ((unsigned)f2bf_rne(a0.y) << 16);
    pa.y = (unsigned)f2bf_rne(a0.z) | ((unsigned)f2bf_rne(a0.w) << 16);
    pa.z = (unsigned)f2bf_rne(a1.x) | ((unsigned)f2bf_rne(a1.y) << 16);
    pa.w = (unsigned)f2bf_rne(a1.z) | ((unsigned)f2bf_rne(a1.w) << 16);
    pb.x = (unsigned)f2bf_rne(b0.x) | ((unsigned)f2bf_rne(b0.y) << 16);
    pb.y = (unsigned)f2bf_rne(b0.z) | ((unsigned)f2bf_rne(b0.w) << 16);
    pb.z = (unsigned)f2bf_rne(b1.x) | ((unsigned)f2bf_rne(b1.y) << 16);
    pb.w = (unsigned)f2bf_rne(b1.z) | ((unsigned)f2bf_rne(b1.w) << 16);
    *(uint4*)(featbf + (size_t)row * 512 + c * 8) = pa;
    *(uint4*)(featbf + (size_t)row * 512 + 256 + c * 8) = pb;
    float p = a0.x * b0.x + a0.y * b0.y + a0.z * b0.z + a0.w * b0.w
            + a1.x * b1.x + a1.y * b1.y + a1.z * b1.z + a1.w * b1.w;
#pragma unroll
    for (int o = 16; o; o >>= 1) p += __shfl_xor(p, o, 32);
    if (c == 0) red[threadIdx.x >> 5] = sat_exp(p);
    __syncthreads();
    if (threadIdx.x == 0) {
        float s = 0.0f;
#pragma unroll
        for (int i = 0; i < 8; ++i) s += red[i];
        partialPos[blockIdx.x] = s;
    }
}

// ---------------- stage1: operand-swapped bf16 MFMA GEMM, sort-merge top-16 ---
// Structure identical to R6 (validated); scan phase now batch bitonic sort-merge.
#define A_OFF 32768
#define S1_LDS 40960

__global__ __launch_bounds__(256, 4) void stage1(const unsigned short* __restrict__ featbf,
                                                 float* __restrict__ wsTop) {
    __shared__ __align__(16) char smem[S1_LDS];
    const int t = threadIdx.x;
    const int l = t & 63;
    const int w = t >> 6;
    const int wy = w >> 1, wx = w & 1;
    const int quad = l >> 4, lane16 = l & 15;
    const int nbase = blockIdx.x * 64;
    const int strip = blockIdx.y;

    // ---- stage B resident: rows nbase..nbase+63 (F1), all K. 8 insts/wave. ----
#pragma unroll
    for (int jj = 0; jj < 8; ++jj) {
        int j = w * 8 + jj;
        int r = 2 * j + (l >> 5);
        int c = (l & 31) ^ (r & 31);
        gld_lds16(featbf + ((size_t)(nbase + r) << 9) + c * 8, smem + j * 1024);
    }

    float lst[2][16];
#pragma unroll
    for (int ni = 0; ni < 2; ++ni)
#pragma unroll
        for (int i = 0; i < 16; ++i) lst[ni][i] = -INFINITY;

    const int akey = (quad ^ ((lane16 >> 1) & 3)) * 16;   // A frag slot offset

#pragma unroll 1
    for (int ct = 0; ct < 8; ++ct) {
        const int ctbase = strip * 1024 + ct * 128;
        v4f acc[4][2];
#pragma unroll
        for (int mi = 0; mi < 4; ++mi)
#pragma unroll
            for (int ni = 0; ni < 2; ++ni) acc[mi][ni] = (v4f)0.0f;

#pragma unroll
        for (int s = 0; s < 8; ++s) {
            __syncthreads();   // prev step's A frag reads done before restage
#pragma unroll
            for (int jj = 0; jj < 2; ++jj) {
                int j = w * 2 + jj;
                int r = 16 * j + (l >> 2);
                int c = (l & 3) ^ ((r >> 1) & 3);
                gld_lds16(featbf + ((size_t)(ctbase + r) << 9) + 256 + s * 32 + c * 8,
                          smem + A_OFF + j * 1024);
            }
            __syncthreads();   // vmcnt(0) drain: staging visible
            s8b a[4];
#pragma unroll
            for (int mi = 0; mi < 4; ++mi)
                a[mi] = *(const s8b*)(smem + A_OFF
                    + (wx * 64 + mi * 16 + lane16) * 64 + akey);
#pragma unroll
            for (int ni = 0; ni < 2; ++ni) {
                int nl31 = ni * 16 + lane16;   // n_local & 31
                s8b b = *(const s8b*)(smem
                    + (wy * 32 + nl31) * 512 + (((s * 4 + quad) ^ nl31) & 31) * 16);
#pragma unroll
                for (int mi = 0; mi < 4; ++mi)
                    acc[mi][ni] = __builtin_amdgcn_mfma_f32_16x16x32_bf16(a[mi], b, acc[mi][ni], 0, 0, 0);
            }
        }
        // ---- batch scan: lane's 16 fresh values per ni -> sort16 + merge ----
#pragma unroll
        for (int ni = 0; ni < 2; ++ni) {
            const int row = nbase + wy * 32 + ni * 16 + lane16;
            float nw[16];
#pragma unroll
            for (int mi = 0; mi < 4; ++mi) {
                const int c0 = ctbase + wx * 64 + mi * 16 + quad * 4;
#pragma unroll
                for (int r4 = 0; r4 < 4; ++r4) {
                    float v = acc[mi][ni][r4];
                    nw[mi * 4 + r4] = (c0 + r4 == row) ? -INFINITY : v;
                }
            }
            sort16(nw);
            merge_top16(lst[ni], nw);
        }
    }
    // ---- quad merge via xor-shfl: lists sorted; 2 bitonic merge rounds ----
#pragma unroll
    for (int ni = 0; ni < 2; ++ni) {
#pragma unroll
        for (int r = 16; r <= 32; r <<= 1) {
            float nw[16];
#pragma unroll
            for (int i = 0; i < 16; ++i) nw[i] = __shfl(lst[ni][i], l ^ r, 64);
            merge_top16(lst[ni], nw);
        }
    }
    // ---- wx merge via LDS (A region free after final barrier) ----
    __syncthreads();
    float* mrg = (float*)(smem + A_OFF);   // 64 rows x 16 f32 = 4 KB
    if (wx == 1 && quad == 0) {
#pragma unroll
        for (int ni = 0; ni < 2; ++ni) {
            int rl = wy * 32 + ni * 16 + lane16;
#pragma unroll
            for (int i = 0; i < 16; i += 4)
                *(v4f*)(mrg + rl * 16 + i) = *(v4f*)&lst[ni][i];
        }
    }
    __syncthreads();
    if (wx == 0 && quad == 0) {
#pragma unroll
        for (int ni = 0; ni < 2; ++ni) {
            const int rl = wy * 32 + ni * 16 + lane16;
            float nw[16];
#pragma unroll
            for (int i = 0; i < 16; ++i) nw[i] = mrg[rl * 16 + i];
            merge_top16(lst[ni], nw);
            float* dst = wsTop + ((size_t)(nbase + rl) * NSTRIPS + strip) * 16;
#pragma unroll
            for (int i = 0; i < 16; i += 4)
                *(float4*)(dst + i) = make_float4(lst[ni][i], lst[ni][i + 1],
                                                  lst[ni][i + 2], lst[ni][i + 3]);
        }
    }
}

// ------- stage2: per-row merge of 128 candidates -> top-16 -> partial sums ----
__global__ void stage2(const float* __restrict__ wsTop, float* __restrict__ partialNeg) {
    __shared__ float red[256];
    int row = blockIdx.x * 256 + threadIdx.x;
    const float* src = wsTop + (size_t)row * (NSTRIPS * 16);
    float lst[16];
#pragma unroll
    for (int i = 0; i < 16; ++i) lst[i] = src[i];   // strip 0 list (sorted asc)
#pragma unroll 1
    for (int c = 16; c < NSTRIPS * 16; c += 16) {
        float nw[16];
#pragma unroll
        for (int i = 0; i < 16; i += 4) {
            float4 v4 = *(const float4*)(src + c + i);
            nw[i] = v4.x; nw[i + 1] = v4.y; nw[i + 2] = v4.z; nw[i + 3] = v4.w;
        }
        merge_top16(lst, nw);   // per-strip lists already sorted ascending
    }
    float s = 0.0f;
#pragma unroll
    for (int i = 0; i < 16; ++i) s += sat_exp(lst[i]);
    red[threadIdx.x] = s;
    __syncthreads();
    for (int o = 128; o; o >>= 1) {
        if (threadIdx.x < o) red[threadIdx.x] += red[threadIdx.x + o];
        __syncthreads();
    }
    if (threadIdx.x == 0) partialNeg[blockIdx.x] = red[0];
}

// ---------------- final: reduce partials, sanitize inf/nan ----------------
__global__ void final_kernel(const float* __restrict__ partialPos,
                             const float* __restrict__ partialNeg,
                             float* __restrict__ out) {
    __shared__ float w1[4], w2[4];
    float sp = 0.0f, sn = 0.0f;
    for (int i = threadIdx.x; i < 1024; i += 256) sp += partialPos[i];
    if (threadIdx.x < 32) sn = partialNeg[threadIdx.x];
#pragma unroll
    for (int o = 32; o; o >>= 1) {
        sp += __shfl_xor(sp, o, 64);
        sn += __shfl_xor(sn, o, 64);
    }
    if ((threadIdx.x & 63) == 0) {
        w1[threadIdx.x >> 6] = sp;
        w2[threadIdx.x >> 6] = sn;
    }
    __syncthreads();
    if (threadIdx.x == 0) {
        float tp = w1[0] + w1[1] + w1[2] + w1[3];
        float tn = w2[0] + w2[1] + w2[2] + w2[3];
        out[0] = finite_or(-(tp / (float)BS), 0.0f);
        out[1] = finite_or(tn / (float)(BS * KNEG), 0.0f);
    }
}

// ======================= legacy fallback (ws too small) ======================
__global__ void init_acc(float* acc) {
    if (threadIdx.x < 64) acc[threadIdx.x] = 0.0f;
}

__global__ void pos_kernel(const float* __restrict__ feat, float* __restrict__ acc) {
    int t = blockIdx.x * 256 + threadIdx.x;
    int row = t >> 4;
    int lane16 = t & 15;
    const float* f = feat + (size_t)row * 512 + lane16 * 16;
    float p = 0.0f;
#pragma unroll
    for (int q = 0; q < 16; q += 4) {
        float4 a = *(const float4*)(f + q);
        float4 b = *(const float4*)(f + 256 + q);
        p += a.x * b.x + a.y * b.y + a.z * b.z + a.w * b.w;
    }
#pragma unroll
    for (int o = 8; o; o >>= 1) p += __shfl_xor(p, o, 16);
    if (lane16 == 0) atomicAdd(&acc[0], sat_exp(p));
}

#define L_AOFF   0
#define L_BOFF   10240
#define L_PITCH  80
#define CPITCH  272
#define CWAVE   17408
#define L_SMEM  69632
__global__ __launch_bounds__(256, 2) void stage1_legacy(const float* __restrict__ feat,
                                                        float* __restrict__ wsTop) {
    __shared__ __align__(16) char smem[L_SMEM];
    const int t = threadIdx.x;
    const int l = t & 63;
    const int w = t >> 6;
    const int wy = w >> 1, wx = w & 1;
    const int quad = l >> 4, lane16 = l & 15;
    const int rowbase = blockIdx.x * 128;
    const int strip = blockIdx.y;
    char* cw = smem + w * CWAVE;
    const int grow = rowbase + wy * 64 + l;

    float lst[16];
#pragma unroll
    for (int i = 0; i < 16; ++i) lst[i] = -INFINITY;

    for (int ct = 0; ct < 4; ++ct) {
        const int colbase = strip * 1024 + ct * 256;
        v4f acc[4][8];
#pragma unroll
        for (int mi = 0; mi < 4; ++mi)
#pragma unroll
            for (int ni = 0; ni < 8; ++ni) acc[mi][ni] = (v4f)0.0f;
        for (int s = 0; s < 8; ++s) {
            const int k0 = s * 32;
            __syncthreads();
#pragma unroll
            for (int i = 0; i < 4; ++i) {
                int c = i * 256 + t;
                int r = c >> 3, chk = c & 7;
                float4 v = *(const float4*)(feat + (size_t)(rowbase + r) * 512 + k0 + chk * 4);
                uint2 pk;
                pk.x = (unsigned)f2bf_rne(v.x) | ((unsigned)f2bf_rne(v.y) << 16);
                pk.y = (unsigned)f2bf_rne(v.z) | ((unsigned)f2bf_rne(v.w) << 16);
                *(uint2*)(smem + L_AOFF + r * L_PITCH + chk * 8) = pk;
            }
#pragma unroll
            for (int i = 0; i < 8; ++i) {
                int c = i * 256 + t;
                int n = c >> 3, chk = c & 7;
                float4 v = *(const float4*)(feat + (size_t)(colbase + n) * 512 + 256 + k0 + chk * 4);
                uint2 pk;
                pk.x = (unsigned)f2bf_rne(v.x) | ((unsigned)f2bf_rne(v.y) << 16);
                pk.y = (unsigned)f2bf_rne(v.z) | ((unsigned)f2bf_rne(v.w) << 16);
                *(uint2*)(smem + L_BOFF + n * L_PITCH + chk * 8) = pk;
            }
            __syncthreads();
            s8b a[4];
#pragma unroll
            for (int mi = 0; mi < 4; ++mi)
                a[mi] = *(const s8b*)(smem + L_AOFF + (wy * 64 + mi * 16 + lane16) * L_PITCH + quad * 16);
#pragma unroll
            for (int ni = 0; ni < 8; ++ni) {
                s8b b = *(const s8b*)(smem + L_BOFF + (wx * 128 + ni * 16 + lane16) * L_PITCH + quad * 16);
#pragma unroll
                for (int mi = 0; mi < 4; ++mi)
                    acc[mi][ni] = __builtin_amdgcn_mfma_f32_16x16x32_bf16(a[mi], b, acc[mi][ni], 0, 0, 0);
            }
        }
#pragma unroll
        for (int h = 0; h < 2; ++h) {
            __syncthreads();
#pragma unroll
            for (int ni = 0; ni < 4; ++ni) {
                int c = ni * 16 + lane16;
#pragma unroll
                for (int mi = 0; mi < 4; ++mi)
                    *(v4f*)(cw + c * CPITCH + mi * 64 + quad * 16) = acc[mi][h * 4 + ni];
            }
            __syncthreads();
            const int gc0 = colbase + wx * 128 + h * 64;
            const int dj = grow - gc0;
#pragma unroll
            for (int j = 0; j < 64; ++j) {
                float v = *(const float*)(cw + j * CPITCH + l * 4);
                if (v > lst[0] && j != dj) topk_insert(lst, v);
            }
        }
    }
    float* dst = wsTop + (size_t)grow * 256 + strip * 32 + wx * 16;
#pragma unroll
    for (int i = 0; i < 16; i += 4)
        *(float4*)(dst + i) = make_float4(lst[i], lst[i + 1], lst[i + 2], lst[i + 3]);
}

__global__ void stage2_legacy(const float* __restrict__ wsTop, float* __restrict__ acc) {
    int row = blockIdx.x * blockDim.x + threadIdx.x;
    if (row >= BS) return;
    const float* src = wsTop + (size_t)row * 256;
    float lst[16];
#pragma unroll
    for (int i = 0; i < 16; ++i) lst[i] = -INFINITY;
    for (int c = 0; c < 256; c += 4) {
        float4 v4 = *(const float4*)(src + c);
        float vv[4] = {v4.x, v4.y, v4.z, v4.w};
#pragma unroll
        for (int j = 0; j < 4; ++j)
            if (vv[j] > lst[0]) topk_insert(lst, vv[j]);
    }
    float s = 0.0f;
#pragma unroll
    for (int i = 0; i < 16; ++i) s += sat_exp(lst[i]);
    atomicAdd(&acc[1], s);
}

__global__ void final_legacy(const float* __restrict__ acc, float* __restrict__ out) {
    if (threadIdx.x == 0) {
        out[0] = finite_or(-(acc[0] / (float)BS), 0.0f);
        out[1] = finite_or(acc[1] / (float)(BS * KNEG), 0.0f);
    }
}

extern "C" void kernel_launch(void* const* d_in, const int* in_sizes, int n_in,
                              void* d_out, int out_size, void* d_ws, size_t ws_size,
                              hipStream_t stream) {
    const float* feat = (const float*)d_in[0];
    float* out = (float*)d_out;

    // new path layout: featbf 8 MB | wsTop 4 MB | partialPos 4 KB | partialNeg 128 B
    unsigned short* featbf = (unsigned short*)d_ws;
    float* wsTop = (float*)(featbf + (size_t)BS * 512);
    float* partialPos = wsTop + (size_t)BS * NSTRIPS * 16;
    float* partialNeg = partialPos + 1024;
    const size_t need_new = (size_t)BS * 512 * 2 + (size_t)BS * NSTRIPS * 16 * 4
                          + (1024 + 32) * 4;

    if (ws_size >= need_new) {
        conv_pos<<<1024, 256, 0, stream>>>(feat, featbf, partialPos);
        stage1<<<dim3(128, NSTRIPS), 256, 0, stream>>>(featbf, wsTop);
        stage2<<<32, 256, 0, stream>>>(wsTop, partialNeg);
        final_kernel<<<1, 256, 0, stream>>>(partialPos, partialNeg, out);
    } else {
        float* acc = (float*)d_ws;
        float* wsTopL = acc + 64;   // 8 MB legacy layout
        init_acc<<<1, 64, 0, stream>>>(acc);
        pos_kernel<<<512, 256, 0, stream>>>(feat, acc);
        stage1_legacy<<<dim3(64, 8), 256, 0, stream>>>(feat, wsTopL);
        stage2_legacy<<<32, 256, 0, stream>>>(wsTopL, acc);
        final_legacy<<<1, 1, 0, stream>>>(acc, out);
    }
}